// Round 12
// baseline (34305.228 us; speedup 1.0000x reference)
//
#include <hip/hip_runtime.h>
#include <math.h>

#define T_STEPS 512
#define BATCH   64
#define INDIM   512
#define MEMDIM  512
#define NWG     512
#define NT      512

// 8 independent groups (g = wg&7, heuristically one XCD): group g scans batch
// rows [8g,8g+8). Member m = wg>>3 (0..63) owns mem dims [8m,8m+8) -> 32 gate
// rows. 2 WGs/CU x 512 thr. h-weights LDS-stationary (66KB); x-weights
// streamed from L2 each step (pre-wait, overlapped). h exchange: write-once
// sc1 ring (IF$) + plain cached reads (proven R11); per-wave wait on only its
// 8 producers (64-dim slice = 2 full cache lines = those producers exactly).
// Thread (w=tid>>6, b=lane>>3, k8=lane&7): k-chunk = dims [64w+8k8, +8);
// acc[32 rows]; 3-stage shfl_xor reduce over k8; part[8][32][9] in LDS;
// 64-thread epilogue; deferred out stores. Groups never sync with each other.

#define SMEM_FLOATS (32*520 + 8*32*9 + 64 + 32)

extern "C" __global__ void __launch_bounds__(NT, 4)
lstm_scan(const float* __restrict__ inputs, const float* __restrict__ h0,
          const float* __restrict__ c0,
          const float* __restrict__ W_ioux, const float* __restrict__ b_ioux,
          const float* __restrict__ W_iouh, const float* __restrict__ b_iouh,
          const float* __restrict__ W_fx,   const float* __restrict__ b_fx,
          const float* __restrict__ W_fh,   const float* __restrict__ b_fh,
          float* __restrict__ out, int* __restrict__ bar, int ring)
{
    extern __shared__ float smem[];
    float* w_s    = smem;                       // [32][520] h-side weights
    float* part   = smem + 32*520;              // [8][32][9]
    float* c_s    = part + 8*32*9;              // [64] (d*8+b)
    float* bias_s = c_s + 64;                   // [32]

    float* ringbuf = (float*)(bar + 2048);      // ring[t][g8][b8][512] at ws+8KB

    const int tid  = threadIdx.x;
    const int wg   = blockIdx.x;
    const int g    = wg & 7;                    // group (batch slice)
    const int m    = wg >> 3;                   // member (dim slice)
    const int w    = tid >> 6;                  // wave 0..7 (k-slice [64w,+64))
    const int lane = tid & 63;
    const int b    = lane >> 3;                 // batch row in group
    const int k8   = lane & 7;                  // k-chunk within wave slice
    const int kbase = w * 64 + k8 * 8;          // first of 8 k-dims

    // ---- prologue: h-weights -> LDS ----
    for (int i = tid; i < 32 * 128; i += NT) {  // 128 float4 per row
        int r = i >> 7, c4 = i & 127;
        int gate = r >> 3, dd = r & 7;
        const float* src = (gate < 3)
            ? (W_iouh + ((size_t)(gate * 512 + 8 * m + dd)) * MEMDIM + c4 * 4)
            : (W_fh   + ((size_t)(8 * m + dd)) * MEMDIM + c4 * 4);
        float4 v = *(const float4*)src;
        *(float4*)&w_s[r * 520 + c4 * 4] = v;
    }
    if (tid < 32) {
        int gate = tid >> 3, dd = tid & 7;
        bias_s[tid] = (gate < 3)
            ? (b_ioux[gate * 512 + 8 * m + dd] + b_iouh[gate * 512 + 8 * m + dd])
            : (b_fx[8 * m + dd] + b_fh[8 * m + dd]);
    }
    if (tid < 64) {
        int d = tid >> 3, bb = tid & 7;
        c_s[tid] = c0[(size_t)(8 * g + bb) * MEMDIM + 8 * m + d];
        float hv = h0[(size_t)(8 * g + bb) * MEMDIM + 8 * m + d];
        __hip_atomic_store(&ringbuf[(size_t)g * 4096 + bb * 512 + 8 * m + d], hv,
                           __ATOMIC_RELAXED, __HIP_MEMORY_SCOPE_AGENT);
    }
    __syncthreads();   // LDS ready; ring[0] stores drained (vmcnt)

    if (tid == 0) {    // arrive epoch 1 (ring[0] slice ready)
        __hip_atomic_store(&bar[m * 8 + g], 1, __ATOMIC_RELAXED,
                           __HIP_MEMORY_SCOPE_AGENT);
    }

    // x-weight bases (stream from L2 each step)
    const float* baseX = W_ioux + (size_t)8 * m * INDIM;   // + gate*512*512 + dd*512
    const float* baseF = W_fx   + (size_t)8 * m * INDIM;

    for (int t = 0; t < T_STEPS; ++t) {
        // ---- x-side dot (pre-wait; x-weights from L2, x-in cached) ----
        float acc[32];
#pragma unroll
        for (int r = 0; r < 32; ++r) acc[r] = 0.f;
        {
            const float* xin = inputs + ((size_t)t * BATCH + 8 * g + b) * INDIM + kbase;
            float4 xv0 = *(const float4*)xin;
            float4 xv1 = *(const float4*)(xin + 4);
#pragma unroll
            for (int r = 0; r < 32; ++r) {
                const float* wp = (r < 24)
                    ? (baseX + ((size_t)((r >> 3) * 512 + (r & 7))) * INDIM + kbase)
                    : (baseF + ((size_t)(r & 7)) * INDIM + kbase);
                float4 w0 = *(const float4*)wp;
                float4 w1 = *(const float4*)(wp + 4);
                acc[r] += w0.x * xv0.x + w0.y * xv0.y + w0.z * xv0.z + w0.w * xv0.w
                        + w1.x * xv1.x + w1.y * xv1.y + w1.z * xv1.z + w1.w * xv1.w;
            }
        }

        // ---- wait: only this wave's 8 producers (members 8w..8w+7) ----
        {
            const int need = t + 1;
            for (;;) {
                int e = 0x7fffffff;
                if (lane < 8)
                    e = __hip_atomic_load(&bar[(8 * w + lane) * 8 + g],
                                          __ATOMIC_RELAXED, __HIP_MEMORY_SCOPE_AGENT);
                if (__all(e >= need)) break;
                __builtin_amdgcn_s_sleep(1);
            }
            asm volatile("" ::: "memory");
        }

        // ---- h-side dot (h-weights LDS, 8-way b-broadcast reads) ----
        {
            size_t slot = ring ? (size_t)t : (size_t)(t & 1);
            const float* hbase = ringbuf + slot * 32768 + (size_t)g * 4096
                               + b * 512 + kbase;
            float4 hv0, hv1;
            if (ring) {
                hv0 = *(const float4*)hbase;
                hv1 = *(const float4*)(hbase + 4);
            } else {
                const unsigned long long* hp = (const unsigned long long*)hbase;
                unsigned long long u0 = __hip_atomic_load(hp + 0, __ATOMIC_RELAXED, __HIP_MEMORY_SCOPE_AGENT);
                unsigned long long u1 = __hip_atomic_load(hp + 1, __ATOMIC_RELAXED, __HIP_MEMORY_SCOPE_AGENT);
                unsigned long long u2 = __hip_atomic_load(hp + 2, __ATOMIC_RELAXED, __HIP_MEMORY_SCOPE_AGENT);
                unsigned long long u3 = __hip_atomic_load(hp + 3, __ATOMIC_RELAXED, __HIP_MEMORY_SCOPE_AGENT);
                float2 f0 = __builtin_bit_cast(float2, u0);
                float2 f1 = __builtin_bit_cast(float2, u1);
                float2 f2 = __builtin_bit_cast(float2, u2);
                float2 f3 = __builtin_bit_cast(float2, u3);
                hv0 = make_float4(f0.x, f0.y, f1.x, f1.y);
                hv1 = make_float4(f2.x, f2.y, f3.x, f3.y);
            }
#pragma unroll
            for (int r = 0; r < 32; ++r) {
                const float* wp = &w_s[r * 520 + kbase];
                float4 w0 = *(const float4*)wp;
                float4 w1 = *(const float4*)(wp + 4);
                acc[r] += w0.x * hv0.x + w0.y * hv0.y + w0.z * hv0.z + w0.w * hv0.w
                        + w1.x * hv1.x + w1.y * hv1.y + w1.z * hv1.z + w1.w * hv1.w;
            }
        }

        // ---- reduce over k8 (3-stage butterfly), write parts ----
#pragma unroll
        for (int r = 0; r < 32; ++r) {
            acc[r] += __shfl_xor(acc[r], 1);
            acc[r] += __shfl_xor(acc[r], 2);
            acc[r] += __shfl_xor(acc[r], 4);
        }
#pragma unroll
        for (int j = 0; j < 4; ++j) {
            int row = 4 * k8 + j;
            part[w * 288 + row * 9 + b] = acc[row];
        }
        __syncthreads();

        // ---- epilogue: 64 threads (d,b): gates, activations, c/h ----
        float hn = 0.f, cn = 0.f;
        int d = tid >> 3, bb = tid & 7;
        if (tid < 64) {
            float gate_v[4];
#pragma unroll
            for (int gate = 0; gate < 4; ++gate) {
                int row = gate * 8 + d;
                float v = bias_s[row];
#pragma unroll
                for (int ww = 0; ww < 8; ++ww) v += part[ww * 288 + row * 9 + bb];
                gate_v[gate] = v;
            }
            float ig = 1.f / (1.f + expf(-gate_v[0]));
            float og = 1.f / (1.f + expf(-gate_v[1]));
            float ug = tanhf(gate_v[2]);
            float fg = 1.f / (1.f + expf(-gate_v[3]));
            cn = ig * ug + fg * c_s[tid];
            c_s[tid] = cn;
            hn = og * tanhf(cn);
            size_t wslot = ring ? (size_t)(t + 1) : (size_t)((t + 1) & 1);
            __hip_atomic_store(&ringbuf[wslot * 32768 + (size_t)g * 4096
                                        + bb * 512 + 8 * m + d], hn,
                               __ATOMIC_RELAXED, __HIP_MEMORY_SCOPE_AGENT);
        }
        __syncthreads();   // drains ring stores (vmcnt) before the arrive

        // ---- arrive epoch t+2 ----
        if (tid == 0) {
            __hip_atomic_store(&bar[m * 8 + g], t + 2, __ATOMIC_RELAXED,
                               __HIP_MEMORY_SCOPE_AGENT);
        }

        // ---- deferred out stores (off the critical path) ----
        if (tid < 64) {
            out[((size_t)t * BATCH + 8 * g + bb) * MEMDIM + 8 * m + d] = hn;
            if (t == T_STEPS - 1) {
                out[(size_t)T_STEPS * BATCH * MEMDIM
                    + (size_t)(8 * g + bb) * MEMDIM + 8 * m + d] = cn;
                out[(size_t)T_STEPS * BATCH * MEMDIM + (size_t)BATCH * MEMDIM
                    + (size_t)(8 * g + bb) * MEMDIM + 8 * m + d] = hn;
            }
        }
    }
}

extern "C" void kernel_launch(void* const* d_in, const int* in_sizes, int n_in,
                              void* d_out, int out_size, void* d_ws, size_t ws_size,
                              hipStream_t stream) {
    (void)in_sizes; (void)n_in; (void)out_size;
    const float* inputs = (const float*)d_in[0];
    const float* h0     = (const float*)d_in[1];
    const float* c0     = (const float*)d_in[2];
    const float* W_ioux = (const float*)d_in[3];
    const float* b_ioux = (const float*)d_in[4];
    const float* W_iouh = (const float*)d_in[5];
    const float* b_iouh = (const float*)d_in[6];
    const float* W_fx   = (const float*)d_in[7];
    const float* b_fx   = (const float*)d_in[8];
    const float* W_fh   = (const float*)d_in[9];
    const float* b_fh   = (const float*)d_in[10];
    float* out = (float*)d_out;
    int*   bar = (int*)d_ws;

    // ring needs 8KB flags + 513 * 128KB
    const size_t need_ring = 8192 + (size_t)513 * 32768 * 4;
    int ring = (ws_size >= need_ring) ? 1 : 0;

    const size_t smem_bytes = SMEM_FLOATS * sizeof(float);   // ~76 KB -> 2 WG/CU
    (void)hipFuncSetAttribute((const void*)lstm_scan,
                              hipFuncAttributeMaxDynamicSharedMemorySize,
                              (int)smem_bytes);

    // zero flags (first 8KB of ws)
    (void)hipMemsetAsync(d_ws, 0, 8192, stream);

    void* args[] = { (void*)&inputs, (void*)&h0, (void*)&c0,
                     (void*)&W_ioux, (void*)&b_ioux, (void*)&W_iouh, (void*)&b_iouh,
                     (void*)&W_fx, (void*)&b_fx, (void*)&W_fh, (void*)&b_fh,
                     (void*)&out, (void*)&bar, (void*)&ring };

    hipError_t err = hipLaunchCooperativeKernel((const void*)lstm_scan,
                                                dim3(NWG), dim3(NT),
                                                args, smem_bytes, stream);
    if (err != hipSuccess) {
        hipLaunchKernelGGL(lstm_scan, dim3(NWG), dim3(NT), smem_bytes, stream,
                           inputs, h0, c0, W_ioux, b_ioux, W_iouh, b_iouh,
                           W_fx, b_fx, W_fh, b_fh, out, bar, ring);
    }
}